// Round 9
// baseline (210.472 us; speedup 1.0000x reference)
//
#include <hip/hip_runtime.h>
#include <stdint.h>

#define SLEN 2048
#define EDIM 1024
#define NH 16
#define HD 64
#define QLD 1152   // qkv packed row: [q 0..1023 | k 1024..1087 | v 1088..1151]

typedef unsigned short u16;
typedef short bf8 __attribute__((ext_vector_type(8)));   // 8 bf16 in 4 VGPRs
typedef float f4 __attribute__((ext_vector_type(4)));
typedef bf8 bf8_a __attribute__((may_alias));
typedef uint2 uint2_a __attribute__((may_alias));
typedef uint4 uint4_a __attribute__((may_alias));

__device__ __forceinline__ float bf2f(u16 u) {
  union { unsigned u; float f; } c; c.u = ((unsigned)u) << 16; return c.f;
}
// HW bf16 convert (RNE): lowers to gfx950 cvt instr(s), ~4x fewer VALU ops
// than the manual round-and-shift sequence.
__device__ __forceinline__ u16 f2bf(float x) {
  union { __bf16 h; u16 u; } c; c.h = (__bf16)x; return c.u;
}
__device__ __forceinline__ unsigned pk2bf(float a, float b) {
  union { __bf16 h[2]; unsigned u; } c;
  c.h[0] = (__bf16)a; c.h[1] = (__bf16)b;
  return c.u;
}
__device__ __forceinline__ void async_cp16(u16* lds, const u16* g) {
  __builtin_amdgcn_global_load_lds((__attribute__((address_space(1))) void*)g,
                                   (__attribute__((address_space(3))) void*)lds,
                                   16, 0, 0);
}

// ---------------- dtype probe (fp32 confirmed; kept for robustness) ----------
__global__ void probe_dtype(const unsigned* __restrict__ x, int* __restrict__ flag) {
  __shared__ int red[256];
  const int t = threadIdx.x;
  int cnt = 0;
  for (int i = t; i < 1024; i += 256) {
    unsigned e = (x[i] >> 7) & 0xFFu;
    cnt += (e >= 0x70u && e <= 0x8Fu) ? 1 : 0;
  }
  red[t] = cnt;
  __syncthreads();
  for (int s = 128; s > 0; s >>= 1) {
    if (t < s) red[t] += red[t + s];
    __syncthreads();
  }
  if (t == 0) *flag = (red[0] >= 512) ? 1 : 0;  // 1 = bf16, 0 = fp32
}

// ---------------- x canonicalize: (bf16|fp32) -> bf16 ------------------------
__global__ void convert_x(const void* __restrict__ src, u16* __restrict__ dst,
                          const int* __restrict__ flag) {
  const int i = (blockIdx.x * 256 + threadIdx.x) * 8;
  if (*flag) {
    *(uint4_a*)&dst[i] = *(const uint4_a*)((const u16*)src + i);
  } else {
    const float* s = (const float*)src;
    u16 tmp[8];
#pragma unroll
    for (int j = 0; j < 8; ++j) tmp[j] = f2bf(s[i + j]);
    *(uint4_a*)&dst[i] = *(const uint4_a*)tmp;
  }
}

// ---------------- 64x64 transpose+convert tile helper ------------------------
__device__ __forceinline__ void tcvt_tile(const void* src, int srcLd,
                                          u16* dst, int dstLd, int r0, int c0,
                                          bool isbf) {
  __shared__ u16 tile[64][65];
  const int t = threadIdx.x;
#pragma unroll
  for (int i = 0; i < 16; ++i) {
    int e = i * 256 + t, rr = e >> 6, cc = e & 63;
    size_t idx = (size_t)(r0 + rr) * srcLd + c0 + cc;
    tile[rr][cc] = isbf ? ((const u16*)src)[idx] : f2bf(((const float*)src)[idx]);
  }
  __syncthreads();
#pragma unroll
  for (int i = 0; i < 16; ++i) {
    int e = i * 256 + t, j = e >> 6, ii = e & 63;
    dst[(size_t)(c0 + j) * dstLd + r0 + ii] = tile[ii][j];
  }
}

__global__ void tcvt_qo(const void* wq, u16* wT, const void* wo, u16* woT,
                        const int* __restrict__ flag) {
  const bool isbf = (*flag != 0);
  const int yy = blockIdx.y;
  if (yy < 16) tcvt_tile(wq, 1024, wT, 1024, blockIdx.x * 64, yy * 64, isbf);
  else         tcvt_tile(wo, 1024, woT, 1024, blockIdx.x * 64, (yy - 16) * 64, isbf);
}
__global__ void tcvt_kv(const void* wk, const void* wv, u16* wT,
                        const int* __restrict__ flag) {
  const bool isbf = (*flag != 0);
  if (blockIdx.y == 0)
    tcvt_tile(wk, 64, wT + (size_t)1024 * 1024, 1024, blockIdx.x * 64, 0, isbf);
  else
    tcvt_tile(wv, 64, wT + (size_t)1088 * 1024, 1024, blockIdx.x * 64, 0, isbf);
}

// V -> vT[b][d][s]
__global__ void tpose_v(const u16* __restrict__ qkvb, u16* __restrict__ vTb) {
  __shared__ u16 tile[64][65];
  const int b = blockIdx.y, r0 = blockIdx.x * 64;
  const u16* src = qkvb + (size_t)b * SLEN * QLD + 1088;
  u16* dst = vTb + (size_t)b * 64 * SLEN;
  const int t = threadIdx.x;
#pragma unroll
  for (int i = 0; i < 16; ++i) {
    int e = i * 256 + t, rr = e >> 6, cc = e & 63;
    tile[rr][cc] = src[(size_t)(r0 + rr) * QLD + cc];
  }
  __syncthreads();
#pragma unroll
  for (int i = 0; i < 16; ++i) {
    int e = i * 256 + t, j = e >> 6, ii = e & 63;
    dst[(size_t)j * SLEN + r0 + ii] = tile[ii][j];
  }
}

// ---------------- bias prep --------------------------------------------------
__global__ void prep_bias(const void* bq, const void* bk, const void* bv,
                          const void* bo, float* biasQKV, float* biasOut,
                          const int* __restrict__ flag) {
  const bool isbf = (*flag != 0);
  int i = blockIdx.x * 256 + threadIdx.x;
  auto rd = [&](const void* p, int idx) -> float {
    return isbf ? bf2f(((const u16*)p)[idx]) : ((const float*)p)[idx];
  };
  if (i < 1024) biasQKV[i] = rd(bq, i);
  else if (i < 1088) biasQKV[i] = rd(bk, i - 1024);
  else if (i < 1152) biasQKV[i] = rd(bv, i - 1088);
  int j = i - 1152;
  if (j >= 0 && j < 1024) biasOut[j] = rd(bo, j);
}

// ---------------- 128x128 bf16 GEMM, B^T input, async staging (m97 shape) ----
__global__ __launch_bounds__(256) void gemm_bt_bias(
    const u16* __restrict__ A, const u16* __restrict__ Bt,
    const float* __restrict__ bias, void* __restrict__ C, int K, int ldc,
    int ofp32) {
  __shared__ __align__(16) u16 As[128 * 64];
  __shared__ __align__(16) u16 Bs[128 * 64];
  const int tn0 = blockIdx.x * 128, tm0 = blockIdx.y * 128;
  const int tid = threadIdx.x, wave = tid >> 6, lane = tid & 63;
  const int quad = lane >> 4, l16 = lane & 15;
  const int wm = wave & 1, wn = wave >> 1;

  f4 acc[4][4];
#pragma unroll
  for (int i = 0; i < 4; ++i)
#pragma unroll
    for (int j = 0; j < 4; ++j) acc[i][j] = f4{0.f, 0.f, 0.f, 0.f};

  int slot[4]; size_t aoff[4], boff[4];
#pragma unroll
  for (int i = 0; i < 4; ++i) {
    int s = i * 256 + tid, m = s >> 3, kc = s & 7, c = (kc - m) & 7;
    slot[i] = s;
    aoff[i] = (size_t)(tm0 + m) * K + c * 8;
    boff[i] = (size_t)(tn0 + m) * K + c * 8;
  }
  int ard[4][2], brd[4][2];
#pragma unroll
  for (int mi = 0; mi < 4; ++mi) {
    int m = wm * 64 + mi * 16 + l16;
#pragma unroll
    for (int kk = 0; kk < 2; ++kk)
      ard[mi][kk] = (m * 8 + (((kk * 4 + quad) + m) & 7)) * 8;
  }
#pragma unroll
  for (int ni = 0; ni < 4; ++ni) {
    int n = wn * 64 + ni * 16 + l16;
#pragma unroll
    for (int kk = 0; kk < 2; ++kk)
      brd[ni][kk] = (n * 8 + (((kk * 4 + quad) + n) & 7)) * 8;
  }

  const int kIt = K >> 6;
  for (int it = 0; it < kIt; ++it) {
    __syncthreads();  // prior frag reads done
    const size_t kb = (size_t)it * 64;
#pragma unroll
    for (int i = 0; i < 4; ++i) {
      async_cp16(&As[slot[i] * 8], A + aoff[i] + kb);
      async_cp16(&Bs[slot[i] * 8], Bt + boff[i] + kb);
    }
    __syncthreads();  // drains vmcnt -> staged data visible
#pragma unroll
    for (int kk = 0; kk < 2; ++kk) {
      bf8 af[4], bfr[4];
#pragma unroll
      for (int mi = 0; mi < 4; ++mi) af[mi] = *(const bf8_a*)&As[ard[mi][kk]];
#pragma unroll
      for (int ni = 0; ni < 4; ++ni) bfr[ni] = *(const bf8_a*)&Bs[brd[ni][kk]];
#pragma unroll
      for (int mi = 0; mi < 4; ++mi)
#pragma unroll
        for (int ni = 0; ni < 4; ++ni)
          acc[mi][ni] = __builtin_amdgcn_mfma_f32_16x16x32_bf16(
              af[mi], bfr[ni], acc[mi][ni], 0, 0, 0);
    }
  }

  float bv[4];
#pragma unroll
  for (int ni = 0; ni < 4; ++ni) bv[ni] = bias[tn0 + wn * 64 + ni * 16 + l16];
#pragma unroll
  for (int mi = 0; mi < 4; ++mi) {
    int row0 = tm0 + wm * 64 + mi * 16 + quad * 4;
#pragma unroll
    for (int ni = 0; ni < 4; ++ni) {
      int col = tn0 + wn * 64 + ni * 16 + l16;
#pragma unroll
      for (int r = 0; r < 4; ++r) {
        float v = acc[mi][ni][r] + bv[ni];
        if (ofp32) ((float*)C)[(size_t)(row0 + r) * ldc + col] = v;
        else       ((u16*)C)[(size_t)(row0 + r) * ldc + col] = f2bf(v);
      }
    }
  }
}

// ---------------- flash attention (MQA) --------------------------------------
// 256 threads = 4 waves x 32 q-rows (2 B-frags/wave): halves K/V LDS reads
// per MFMA vs 16-row waves. Fragment-major Kf/Vf/Ps: all b128 reads are
// lane-sequential (conflict-free); Ps b64 writes land 4 dw/bank (balanced).
// No-max softmax (scores bounded: |s*scale| < ~2).
__global__ __launch_bounds__(256, 2) void attn_kernel(
    const u16* __restrict__ qkv, const u16* __restrict__ vT,
    u16* __restrict__ aout) {
  __shared__ __align__(16) u16 Kf[8192];    // K tile frag-major; Qf in prologue
  __shared__ __align__(16) u16 Vf[8192];
  __shared__ __align__(16) u16 Ps[16384];   // 4 waves x 512 chunks x 8
  const int qt = blockIdx.x, bh = blockIdx.y, b = bh >> 4, h = bh & 15;
  const int tid = threadIdx.x, wave = tid >> 6, lane = tid & 63;
  const int quad = lane >> 4, l16 = lane & 15;

  // Qf stage: chunk d = [kk:1][g:3][qd:2][r16:4] -> row g*16+r16, col (kk*4+qd)*8
#pragma unroll
  for (int i = 0; i < 4; ++i) {
    int d = i * 256 + tid;
    int kk = d >> 9, g = (d >> 6) & 7, qd = (d >> 4) & 3, r16 = d & 15;
    async_cp16(&Kf[d * 8],
               qkv + (size_t)(b * SLEN + qt * 128 + g * 16 + r16) * QLD +
                   h * HD + (kk * 4 + qd) * 8);
  }
  __syncthreads();
  bf8 bq[2][2];  // [nt][kk], B-frag rows wave*32 + nt*16 + l16
#pragma unroll
  for (int nt = 0; nt < 2; ++nt)
#pragma unroll
    for (int kk = 0; kk < 2; ++kk)
      bq[nt][kk] = *(const bf8_a*)&Kf[((kk * 8 + wave * 2 + nt) * 64 + lane) * 8];

  f4 acc_o[2][4];
#pragma unroll
  for (int i = 0; i < 2; ++i)
#pragma unroll
    for (int j = 0; j < 4; ++j) acc_o[i][j] = f4{0.f, 0.f, 0.f, 0.f};
  f4 lr4[2] = {f4{0.f, 0.f, 0.f, 0.f}, f4{0.f, 0.f, 0.f, 0.f}};
  const float C1 = 0.125f * 1.44269504089f;  // scale * log2(e)

  for (int kt = 0; kt < 16; ++kt) {
    __syncthreads();  // prior Kf/Vf/Ps reads (incl. bq prologue) complete
    // Kf: chunk d = [kk:1][k8:3][qd:2][r16:4]
#pragma unroll
    for (int i = 0; i < 4; ++i) {
      int d = i * 256 + tid;
      int kk = d >> 9, k8 = (d >> 6) & 7, qd = (d >> 4) & 3, r16 = d & 15;
      async_cp16(&Kf[d * 8],
                 qkv + (size_t)(b * SLEN + kt * 128 + k8 * 16 + r16) * QLD +
                     EDIM + (kk * 4 + qd) * 8);
    }
    // Vf: chunk d = [k4:2][ni:2][qd:2][r16:4]
#pragma unroll
    for (int i = 0; i < 4; ++i) {
      int d = i * 256 + tid;
      int k4 = d >> 8, ni = (d >> 6) & 3, qd = (d >> 4) & 3, r16 = d & 15;
      async_cp16(&Vf[d * 8],
                 vT + (size_t)(b * 64 + ni * 16 + r16) * SLEN + kt * 128 +
                     (k4 * 4 + qd) * 8);
    }
    __syncthreads();

    // S^T = K.Q^T: D[m=key(16 per k8)][n=qrow(16 per nt)]
    f4 st[8][2];
#pragma unroll
    for (int k8 = 0; k8 < 8; ++k8)
#pragma unroll
      for (int nt = 0; nt < 2; ++nt) st[k8][nt] = f4{0.f, 0.f, 0.f, 0.f};
#pragma unroll
    for (int kk = 0; kk < 2; ++kk)
#pragma unroll
      for (int k8 = 0; k8 < 8; ++k8) {
        bf8 ak = *(const bf8_a*)&Kf[((kk * 8 + k8) * 64 + lane) * 8];
#pragma unroll
        for (int nt = 0; nt < 2; ++nt)
          st[k8][nt] = __builtin_amdgcn_mfma_f32_16x16x32_bf16(ak, bq[nt][kk], st[k8][nt], 0, 0, 0);
      }

    // no-max softmax: p = exp2(s*C1); Ps fragment-major (PV A-operand order)
#pragma unroll
    for (int nt = 0; nt < 2; ++nt)
#pragma unroll
      for (int k8 = 0; k8 < 8; ++k8) {
        f4 pe;
        pe[0] = __builtin_amdgcn_exp2f(st[k8][nt][0] * C1);
        pe[1] = __builtin_amdgcn_exp2f(st[k8][nt][1] * C1);
        pe[2] = __builtin_amdgcn_exp2f(st[k8][nt][2] * C1);
        pe[3] = __builtin_amdgcn_exp2f(st[k8][nt][3] * C1);
        lr4[nt] += pe;
        uint2 pk;
        pk.x = pk2bf(pe[0], pe[1]);
        pk.y = pk2bf(pe[2], pe[3]);
        int c = nt * 256 + (k8 >> 1) * 64 + (((k8 << 1) + (quad >> 1)) & 3) * 16 + l16;
        *(uint2_a*)&Ps[(wave * 512 + c) * 8 + (quad & 1) * 4] = pk;
      }
    __syncthreads();  // Ps visible

    // PV: O[qrow][d] += P.V
#pragma unroll
    for (int k4 = 0; k4 < 4; ++k4) {
      bf8 ap[2];
#pragma unroll
      for (int mt = 0; mt < 2; ++mt)
        ap[mt] = *(const bf8_a*)&Ps[(wave * 512 + mt * 256 + k4 * 64 + quad * 16 + l16) * 8];
#pragma unroll
      for (int ni = 0; ni < 4; ++ni) {
        bf8 bv = *(const bf8_a*)&Vf[((k4 * 4 + ni) * 64 + lane) * 8];
#pragma unroll
        for (int mt = 0; mt < 2; ++mt)
          acc_o[mt][ni] = __builtin_amdgcn_mfma_f32_16x16x32_bf16(ap[mt], bv, acc_o[mt][ni], 0, 0, 0);
      }
    }
  }

  // finalize l per qrow and store (C layout: row=quad*4+r, col=l16)
  float ls[2];
#pragma unroll
  for (int nt = 0; nt < 2; ++nt) {
    float s = (lr4[nt][0] + lr4[nt][1]) + (lr4[nt][2] + lr4[nt][3]);
    s += __shfl_xor(s, 16, 64);
    s += __shfl_xor(s, 32, 64);
    ls[nt] = s;
  }
#pragma unroll
  for (int mt = 0; mt < 2; ++mt)
#pragma unroll
    for (int r = 0; r < 4; ++r) {
      float li = __shfl(ls[mt], quad * 4 + r, 64);
      float inv = 1.f / li;
      size_t row = (size_t)(b * SLEN + qt * 128 + wave * 32 + mt * 16 + quad * 4 + r);
#pragma unroll
      for (int ni = 0; ni < 4; ++ni)
        aout[row * EDIM + h * HD + ni * 16 + l16] = f2bf(acc_o[mt][ni][r] * inv);
    }
}

// ---------------- host ------------------------------------------------------
extern "C" void kernel_launch(void* const* d_in, const int* in_sizes, int n_in,
                              void* d_out, int out_size, void* d_ws, size_t ws_size,
                              hipStream_t stream) {
  const void* x  = d_in[0];
  const void* wq = d_in[1];
  const void* bq = d_in[2];
  const void* wk = d_in[3];
  const void* bk = d_in[4];
  const void* wv = d_in[5];
  const void* bv = d_in[6];
  const void* wo = d_in[7];
  const void* bo = d_in[8];

  char* ws = (char*)d_ws;
  size_t off = 0;
  auto carve = [&](size_t bytes) {
    void* p = ws + off;
    off = (off + bytes + 255) & ~(size_t)255;
    return p;
  };
  int* dflag   = (int*)carve(256);
  u16* xbf     = (u16*)carve((size_t)4096 * EDIM * 2);
  u16* wT      = (u16*)carve((size_t)1152 * 1024 * 2);  // packed [wq|wk|wv]^T
  u16* woT     = (u16*)carve((size_t)1024 * 1024 * 2);
  float* bQKV  = (float*)carve(1152 * 4);
  float* bOut  = (float*)carve(1024 * 4);
  u16* qkvb    = (u16*)carve((size_t)4096 * QLD * 2);
  u16* vTb     = (u16*)carve((size_t)2 * 64 * SLEN * 2);
  u16* aob     = (u16*)carve((size_t)4096 * EDIM * 2);

  probe_dtype<<<dim3(1), 256, 0, stream>>>((const unsigned*)x, dflag);
  convert_x<<<dim3(2048), 256, 0, stream>>>(x, xbf, dflag);
  tcvt_qo<<<dim3(16, 32), 256, 0, stream>>>(wq, wT, wo, woT, dflag);
  tcvt_kv<<<dim3(16, 2), 256, 0, stream>>>(wk, wv, wT, dflag);
  prep_bias<<<dim3(9), 256, 0, stream>>>(bq, bk, bv, bo, bQKV, bOut, dflag);

  // QKV projection: [4096][1024] @ [1024][1152] -> qkvb (bf16)
  gemm_bt_bias<<<dim3(9, 32), 256, 0, stream>>>(xbf, wT, bQKV, qkvb, 1024, QLD, 0);

  // V -> vT[b][d][s]
  tpose_v<<<dim3(32, 2), 256, 0, stream>>>(qkvb, vTb);

  // flash attention
  attn_kernel<<<dim3(16, 32), 256, 0, stream>>>(qkvb, vTb, aob);

  // output projection + bo -> d_out (fp32)
  gemm_bt_bias<<<dim3(8, 32), 256, 0, stream>>>(aob, woT, bOut, d_out, 1024, 1024, 1);
}

// Round 10
// 183.655 us; speedup vs baseline: 1.1460x; 1.1460x over previous
//
#include <hip/hip_runtime.h>
#include <stdint.h>

#define SLEN 2048
#define EDIM 1024
#define NH 16
#define HD 64
#define QLD 1152   // qkv packed row: [q 0..1023 | k 1024..1087 | v 1088..1151]

typedef unsigned short u16;
typedef short bf8 __attribute__((ext_vector_type(8)));   // 8 bf16 in 4 VGPRs
typedef float f4 __attribute__((ext_vector_type(4)));
typedef bf8 bf8_a __attribute__((may_alias));
typedef uint2 uint2_a __attribute__((may_alias));
typedef uint4 uint4_a __attribute__((may_alias));

__device__ __forceinline__ u16 f2bf(float x) {
  union { __bf16 h; u16 u; } c; c.h = (__bf16)x; return c.u;  // HW cvt, RNE
}
__device__ __forceinline__ unsigned pk2bf(float a, float b) {
  union { __bf16 h[2]; unsigned u; } c;
  c.h[0] = (__bf16)a; c.h[1] = (__bf16)b;
  return c.u;
}
__device__ __forceinline__ void async_cp16(u16* lds, const u16* g) {
  __builtin_amdgcn_global_load_lds((__attribute__((address_space(1))) void*)g,
                                   (__attribute__((address_space(3))) void*)lds,
                                   16, 0, 0);
}

// ---------------- x: fp32 -> bf16 (dtype fp32 proven R5/R7) ------------------
__global__ void convert_x(const float* __restrict__ src, u16* __restrict__ dst) {
  const int i = (blockIdx.x * 256 + threadIdx.x) * 8;
  u16 tmp[8];
#pragma unroll
  for (int j = 0; j < 8; ++j) tmp[j] = f2bf(src[i + j]);
  *(uint4_a*)&dst[i] = *(const uint4_a*)tmp;
}

// ---------------- fused weight transpose+convert + bias prep -----------------
__device__ __forceinline__ void tcvt_tile(const float* src, int srcLd,
                                          u16* dst, int dstLd, int r0, int c0) {
  __shared__ u16 tile[64][65];
  const int t = threadIdx.x;
#pragma unroll
  for (int i = 0; i < 16; ++i) {
    int e = i * 256 + t, rr = e >> 6, cc = e & 63;
    tile[rr][cc] = f2bf(src[(size_t)(r0 + rr) * srcLd + c0 + cc]);
  }
  __syncthreads();
#pragma unroll
  for (int i = 0; i < 16; ++i) {
    int e = i * 256 + t, j = e >> 6, ii = e & 63;
    dst[(size_t)(c0 + j) * dstLd + r0 + ii] = tile[ii][j];
  }
}

__global__ void prep_w(const float* wq, const float* wk, const float* wv,
                       const float* wo, const float* bq, const float* bk,
                       const float* bv, const float* bo,
                       u16* wT, u16* woT, float* bQKV, float* bOut) {
  const int yy = blockIdx.y;
  if (yy < 16) tcvt_tile(wq, 1024, wT, 1024, blockIdx.x * 64, yy * 64);
  else if (yy < 32) tcvt_tile(wo, 1024, woT, 1024, blockIdx.x * 64, (yy - 16) * 64);
  else if (yy == 32) tcvt_tile(wk, 64, wT + (size_t)1024 * 1024, 1024, blockIdx.x * 64, 0);
  else if (yy == 33) tcvt_tile(wv, 64, wT + (size_t)1088 * 1024, 1024, blockIdx.x * 64, 0);
  else {
    int i = blockIdx.x * 256 + threadIdx.x;
    if (i < 1024) bQKV[i] = bq[i];
    else if (i < 1088) bQKV[i] = bk[i - 1024];
    else if (i < 1152) bQKV[i] = bv[i - 1088];
    int j = i - 1152;
    if (j >= 0 && j < 1024) bOut[j] = bo[j];
  }
}

// ---------------- 64x128 bf16 GEMM, B^T input, async staging -----------------
// R8-proven tile (576/512-block grids). XOR chunk swizzle: chunk c of row m
// at slot m*8 + ((c+m)&7). ofp32: fp32 epilogue (d_out). vtb: if non-null,
// waves covering cols>=1088 also scatter V transposed to vT[b][d][s].
__global__ __launch_bounds__(256) void gemm_bt_bias(
    const u16* __restrict__ A, const u16* __restrict__ Bt,
    const float* __restrict__ bias, void* __restrict__ C, int K, int ldc,
    int ofp32, u16* __restrict__ vtb) {
  __shared__ __align__(16) u16 As[64 * 64];
  __shared__ __align__(16) u16 Bs[128 * 64];
  const int tn0 = blockIdx.x * 128, tm0 = blockIdx.y * 64;
  const int tid = threadIdx.x, wave = tid >> 6, lane = tid & 63;
  const int quad = lane >> 4, l16 = lane & 15;
  const int wm = wave & 1, wn = wave >> 1;

  f4 acc[2][4];
#pragma unroll
  for (int i = 0; i < 2; ++i)
#pragma unroll
    for (int j = 0; j < 4; ++j) acc[i][j] = f4{0.f, 0.f, 0.f, 0.f};

  int aslot[2], bslot[4]; size_t aoff[2], boff[4];
#pragma unroll
  for (int i = 0; i < 2; ++i) {
    int s = i * 256 + tid, m = s >> 3, kc = s & 7, c = (kc - m) & 7;
    aslot[i] = s; aoff[i] = (size_t)(tm0 + m) * K + c * 8;
  }
#pragma unroll
  for (int i = 0; i < 4; ++i) {
    int s = i * 256 + tid, n = s >> 3, kc = s & 7, c = (kc - n) & 7;
    bslot[i] = s; boff[i] = (size_t)(tn0 + n) * K + c * 8;
  }
  int ard[2][2], brd[4][2];
#pragma unroll
  for (int mi = 0; mi < 2; ++mi) {
    int m = wm * 32 + mi * 16 + l16;
#pragma unroll
    for (int kk = 0; kk < 2; ++kk)
      ard[mi][kk] = (m * 8 + (((kk * 4 + quad) + m) & 7)) * 8;
  }
#pragma unroll
  for (int ni = 0; ni < 4; ++ni) {
    int n = wn * 64 + ni * 16 + l16;
#pragma unroll
    for (int kk = 0; kk < 2; ++kk)
      brd[ni][kk] = (n * 8 + (((kk * 4 + quad) + n) & 7)) * 8;
  }

  const int kIt = K >> 6;
  for (int it = 0; it < kIt; ++it) {
    __syncthreads();  // prior frag reads done
    const size_t kb = (size_t)it * 64;
#pragma unroll
    for (int i = 0; i < 2; ++i) async_cp16(&As[aslot[i] * 8], A + aoff[i] + kb);
#pragma unroll
    for (int i = 0; i < 4; ++i) async_cp16(&Bs[bslot[i] * 8], Bt + boff[i] + kb);
    __syncthreads();  // drains vmcnt -> staged data visible
#pragma unroll
    for (int kk = 0; kk < 2; ++kk) {
      bf8 af[2], bfr[4];
#pragma unroll
      for (int mi = 0; mi < 2; ++mi) af[mi] = *(const bf8_a*)&As[ard[mi][kk]];
#pragma unroll
      for (int ni = 0; ni < 4; ++ni) bfr[ni] = *(const bf8_a*)&Bs[brd[ni][kk]];
#pragma unroll
      for (int mi = 0; mi < 2; ++mi)
#pragma unroll
        for (int ni = 0; ni < 4; ++ni)
          acc[mi][ni] = __builtin_amdgcn_mfma_f32_16x16x32_bf16(
              af[mi], bfr[ni], acc[mi][ni], 0, 0, 0);
    }
  }

  float bv[4];
#pragma unroll
  for (int ni = 0; ni < 4; ++ni) bv[ni] = bias[tn0 + wn * 64 + ni * 16 + l16];
#pragma unroll
  for (int mi = 0; mi < 2; ++mi) {
    int row0 = tm0 + wm * 32 + mi * 16 + quad * 4;
#pragma unroll
    for (int ni = 0; ni < 4; ++ni) {
      int col = tn0 + wn * 64 + ni * 16 + l16;
      float vv[4];
#pragma unroll
      for (int r = 0; r < 4; ++r) vv[r] = acc[mi][ni][r] + bv[ni];
      if (ofp32) {
#pragma unroll
        for (int r = 0; r < 4; ++r)
          ((float*)C)[(size_t)(row0 + r) * ldc + col] = vv[r];
      } else {
#pragma unroll
        for (int r = 0; r < 4; ++r)
          ((u16*)C)[(size_t)(row0 + r) * ldc + col] = f2bf(vv[r]);
      }
      if (vtb != nullptr && col >= 1088) {
        // V columns: also write vT[b][d][s0..s0+3] (4 consecutive s, 8B store)
        int d = col - 1088, bb = row0 >> 11, s0 = row0 & 2047;
        uint2 pk;
        pk.x = pk2bf(vv[0], vv[1]);
        pk.y = pk2bf(vv[2], vv[3]);
        *(uint2_a*)&vtb[(size_t)(bb * 64 + d) * SLEN + s0] = pk;
      }
    }
  }
}

// ---------------- flash attention (MQA) --------------------------------------
// 256 thr = 4 waves x 32 q-rows. Fragment-major Kf/Vf (lane-sequential b128,
// conflict-free, async-staged). Per-32-key fused groups: QK -> exp2/pack ->
// wave-private Ps (2KB/wave, no barrier: in-order DS + asm fence) -> PV.
// LDS 40KB -> 4 blocks/CU. No-max softmax (scores bounded small).
__global__ __launch_bounds__(256, 4) void attn_kernel(
    const u16* __restrict__ qkv, const u16* __restrict__ vT,
    u16* __restrict__ aout) {
  __shared__ __align__(16) u16 Kf[8192];    // K tile frag-major; Qf in prologue
  __shared__ __align__(16) u16 Vf[8192];
  __shared__ __align__(16) u16 Ps[4096];    // 4 waves x 1024 (one 32-key group)
  const int qt = blockIdx.x, bh = blockIdx.y, b = bh >> 4, h = bh & 15;
  const int tid = threadIdx.x, wave = tid >> 6, lane = tid & 63;
  const int quad = lane >> 4, l16 = lane & 15;

  // Qf stage: chunk d = [kk:1][g:3][qd:2][r16:4]
#pragma unroll
  for (int i = 0; i < 4; ++i) {
    int d = i * 256 + tid;
    int kk = d >> 9, g = (d >> 6) & 7, qd = (d >> 4) & 3, r16 = d & 15;
    async_cp16(&Kf[d * 8],
               qkv + (size_t)(b * SLEN + qt * 128 + g * 16 + r16) * QLD +
                   h * HD + (kk * 4 + qd) * 8);
  }
  __syncthreads();
  bf8 bq[2][2];  // [nt][kk], B-frag rows wave*32 + nt*16 + l16
#pragma unroll
  for (int nt = 0; nt < 2; ++nt)
#pragma unroll
    for (int kk = 0; kk < 2; ++kk)
      bq[nt][kk] = *(const bf8_a*)&Kf[((kk * 8 + wave * 2 + nt) * 64 + lane) * 8];

  f4 acc_o[2][4];
#pragma unroll
  for (int i = 0; i < 2; ++i)
#pragma unroll
    for (int j = 0; j < 4; ++j) acc_o[i][j] = f4{0.f, 0.f, 0.f, 0.f};
  f4 lr4[2] = {f4{0.f, 0.f, 0.f, 0.f}, f4{0.f, 0.f, 0.f, 0.f}};
  const float C1 = 0.125f * 1.44269504089f;  // scale * log2(e)
  const int psb = wave * 1024;

  for (int kt = 0; kt < 16; ++kt) {
    __syncthreads();  // prior Kf/Vf reads (incl. bq prologue) complete
    // Kf: chunk d = [kk:1][k8:3][qd:2][r16:4]
#pragma unroll
    for (int i = 0; i < 4; ++i) {
      int d = i * 256 + tid;
      int kk = d >> 9, k8 = (d >> 6) & 7, qd = (d >> 4) & 3, r16 = d & 15;
      async_cp16(&Kf[d * 8],
                 qkv + (size_t)(b * SLEN + kt * 128 + k8 * 16 + r16) * QLD +
                     EDIM + (kk * 4 + qd) * 8);
    }
    // Vf: chunk d = [k4:2][ni:2][qd:2][r16:4]
#pragma unroll
    for (int i = 0; i < 4; ++i) {
      int d = i * 256 + tid;
      int k4 = d >> 8, ni = (d >> 6) & 3, qd = (d >> 4) & 3, r16 = d & 15;
      async_cp16(&Vf[d * 8],
                 vT + (size_t)(b * 64 + ni * 16 + r16) * SLEN + kt * 128 +
                     (k4 * 4 + qd) * 8);
    }
    __syncthreads();

    // per-32-key fused groups: QK -> softmax/pack -> Ps -> PV
#pragma unroll
    for (int k4 = 0; k4 < 4; ++k4) {
      f4 st[2][2];  // [j (k8 within group)][nt]
#pragma unroll
      for (int j = 0; j < 2; ++j)
#pragma unroll
        for (int nt = 0; nt < 2; ++nt) st[j][nt] = f4{0.f, 0.f, 0.f, 0.f};
#pragma unroll
      for (int kk = 0; kk < 2; ++kk)
#pragma unroll
        for (int j = 0; j < 2; ++j) {
          bf8 ak = *(const bf8_a*)&Kf[((kk * 8 + k4 * 2 + j) * 64 + lane) * 8];
#pragma unroll
          for (int nt = 0; nt < 2; ++nt)
            st[j][nt] = __builtin_amdgcn_mfma_f32_16x16x32_bf16(
                ak, bq[nt][kk], st[j][nt], 0, 0, 0);
        }
      // exp2 + pack into wave-private Ps (PV A-operand order)
#pragma unroll
      for (int nt = 0; nt < 2; ++nt)
#pragma unroll
        for (int j = 0; j < 2; ++j) {
          f4 pe;
          pe[0] = __builtin_amdgcn_exp2f(st[j][nt][0] * C1);
          pe[1] = __builtin_amdgcn_exp2f(st[j][nt][1] * C1);
          pe[2] = __builtin_amdgcn_exp2f(st[j][nt][2] * C1);
          pe[3] = __builtin_amdgcn_exp2f(st[j][nt][3] * C1);
          lr4[nt] += pe;
          uint2 pk;
          pk.x = pk2bf(pe[0], pe[1]);
          pk.y = pk2bf(pe[2], pe[3]);
          int qd2 = j * 2 + (quad >> 1);
          *(uint2_a*)&Ps[psb + ((nt * 4 + qd2) * 16 + l16) * 8 + (quad & 1) * 4] = pk;
        }
      asm volatile("" ::: "memory");  // Ps writes before PV reads (same wave)
      bf8 ap[2];
#pragma unroll
      for (int mt = 0; mt < 2; ++mt)
        ap[mt] = *(const bf8_a*)&Ps[psb + ((mt * 4 + quad) * 16 + l16) * 8];
#pragma unroll
      for (int ni = 0; ni < 4; ++ni) {
        bf8 bv = *(const bf8_a*)&Vf[((k4 * 4 + ni) * 64 + lane) * 8];
#pragma unroll
        for (int mt = 0; mt < 2; ++mt)
          acc_o[mt][ni] = __builtin_amdgcn_mfma_f32_16x16x32_bf16(
              ap[mt], bv, acc_o[mt][ni], 0, 0, 0);
      }
      asm volatile("" ::: "memory");  // PV reads before next group's Ps writes
    }
  }

  // finalize l per qrow and store (C layout: row=quad*4+r, col=l16)
  float ls[2];
#pragma unroll
  for (int nt = 0; nt < 2; ++nt) {
    float s = (lr4[nt][0] + lr4[nt][1]) + (lr4[nt][2] + lr4[nt][3]);
    s += __shfl_xor(s, 16, 64);
    s += __shfl_xor(s, 32, 64);
    ls[nt] = s;
  }
#pragma unroll
  for (int mt = 0; mt < 2; ++mt)
#pragma unroll
    for (int r = 0; r < 4; ++r) {
      float li = __shfl(ls[mt], quad * 4 + r, 64);
      float inv = 1.f / li;
      size_t row = (size_t)(b * SLEN + qt * 128 + wave * 32 + mt * 16 + quad * 4 + r);
#pragma unroll
      for (int ni = 0; ni < 4; ++ni)
        aout[row * EDIM + h * HD + ni * 16 + l16] = f2bf(acc_o[mt][ni][r] * inv);
    }
}

// ---------------- host ------------------------------------------------------
extern "C" void kernel_launch(void* const* d_in, const int* in_sizes, int n_in,
                              void* d_out, int out_size, void* d_ws, size_t ws_size,
                              hipStream_t stream) {
  const float* x  = (const float*)d_in[0];
  const float* wq = (const float*)d_in[1];
  const float* bq = (const float*)d_in[2];
  const float* wk = (const float*)d_in[3];
  const float* bk = (const float*)d_in[4];
  const float* wv = (const float*)d_in[5];
  const float* bv = (const float*)d_in[6];
  const float* wo = (const float*)d_in[7];
  const float* bo = (const float*)d_in[8];

  char* ws = (char*)d_ws;
  size_t off = 0;
  auto carve = [&](size_t bytes) {
    void* p = ws + off;
    off = (off + bytes + 255) & ~(size_t)255;
    return p;
  };
  u16* xbf     = (u16*)carve((size_t)4096 * EDIM * 2);
  u16* wT      = (u16*)carve((size_t)1152 * 1024 * 2);  // packed [wq|wk|wv]^T
  u16* woT     = (u16*)carve((size_t)1024 * 1024 * 2);
  float* bQKV  = (float*)carve(1152 * 4);
  float* bOut  = (float*)carve(1024 * 4);
  u16* qkvb    = (u16*)carve((size_t)4096 * QLD * 2);
  u16* vTb     = (u16*)carve((size_t)2 * 64 * SLEN * 2);
  u16* aob     = (u16*)carve((size_t)4096 * EDIM * 2);

  convert_x<<<dim3(2048), 256, 0, stream>>>(x, xbf);
  prep_w<<<dim3(16, 35), 256, 0, stream>>>(wq, wk, wv, wo, bq, bk, bv, bo,
                                           wT, woT, bQKV, bOut);

  // QKV projection (+ fused V-transpose): [4096][1024] @ [1024][1152]^T
  gemm_bt_bias<<<dim3(9, 64), 256, 0, stream>>>(xbf, wT, bQKV, qkvb, 1024, QLD,
                                                0, vTb);

  // flash attention
  attn_kernel<<<dim3(16, 32), 256, 0, stream>>>(qkvb, vTb, aob);

  // output projection + bo -> d_out (fp32)
  gemm_bt_bias<<<dim3(8, 64), 256, 0, stream>>>(aob, woT, bOut, d_out, 1024,
                                                1024, 1, nullptr);
}

// Round 11
// 181.892 us; speedup vs baseline: 1.1571x; 1.0097x over previous
//
#include <hip/hip_runtime.h>
#include <stdint.h>

#define SLEN 2048
#define EDIM 1024
#define NH 16
#define HD 64
#define QLD 1152   // qkv packed row: [q 0..1023 | k 1024..1087 | v 1088..1151]

typedef unsigned short u16;
typedef short bf8 __attribute__((ext_vector_type(8)));   // 8 bf16 in 4 VGPRs
typedef float f4 __attribute__((ext_vector_type(4)));
typedef bf8 bf8_a __attribute__((may_alias));
typedef uint2 uint2_a __attribute__((may_alias));
typedef uint4 uint4_a __attribute__((may_alias));

__device__ __forceinline__ float bf2f(u16 u) {
  union { unsigned u; float f; } c; c.u = ((unsigned)u) << 16; return c.f;
}
__device__ __forceinline__ u16 f2bf(float x) {
  union { __bf16 h; u16 u; } c; c.h = (__bf16)x; return c.u;  // HW cvt, RNE
}
__device__ __forceinline__ unsigned pk2bf(float a, float b) {
  union { __bf16 h[2]; unsigned u; } c;
  c.h[0] = (__bf16)a; c.h[1] = (__bf16)b;
  return c.u;
}
__device__ __forceinline__ void async_cp16(u16* lds, const u16* g) {
  __builtin_amdgcn_global_load_lds((__attribute__((address_space(1))) void*)g,
                                   (__attribute__((address_space(3))) void*)lds,
                                   16, 0, 0);
}

// ---------------- fused prep: weight transposes + bias + x-convert -----------
__device__ __forceinline__ void tcvt_tile(const float* src, int srcLd,
                                          u16* dst, int dstLd, int r0, int c0) {
  __shared__ u16 tile[64][65];
  const int t = threadIdx.x;
#pragma unroll
  for (int i = 0; i < 16; ++i) {
    int e = i * 256 + t, rr = e >> 6, cc = e & 63;
    tile[rr][cc] = f2bf(src[(size_t)(r0 + rr) * srcLd + c0 + cc]);
  }
  __syncthreads();
#pragma unroll
  for (int i = 0; i < 16; ++i) {
    int e = i * 256 + t, j = e >> 6, ii = e & 63;
    dst[(size_t)(c0 + j) * dstLd + r0 + ii] = tile[ii][j];
  }
}

__global__ void prep_w(const float* wq, const float* wk, const float* wv,
                       const float* wo, const float* bq, const float* bk,
                       const float* bv, const float* bo, const float* x,
                       u16* wT, u16* woT, float* bQKV, float* bOut, u16* xbf) {
  const int yy = blockIdx.y;
  if (yy < 16) tcvt_tile(wq, 1024, wT, 1024, blockIdx.x * 64, yy * 64);
  else if (yy < 32) tcvt_tile(wo, 1024, woT, 1024, blockIdx.x * 64, (yy - 16) * 64);
  else if (yy == 32) tcvt_tile(wk, 64, wT + (size_t)1024 * 1024, 1024, blockIdx.x * 64, 0);
  else if (yy == 33) tcvt_tile(wv, 64, wT + (size_t)1088 * 1024, 1024, blockIdx.x * 64, 0);
  else if (yy == 34) {
    int i = blockIdx.x * 256 + threadIdx.x;
    if (i < 1024) bQKV[i] = bq[i];
    else if (i < 1088) bQKV[i] = bk[i - 1024];
    else if (i < 1152) bQKV[i] = bv[i - 1088];
    int j = i - 1152;
    if (j >= 0 && j < 1024) bOut[j] = bo[j];
  } else {
    // x fp32 -> bf16: 256 blocks x 256 thr x 64 elems = 4M
    const int blk = (yy - 35) * 16 + blockIdx.x, t = threadIdx.x;
#pragma unroll
    for (int i = 0; i < 8; ++i) {
      int idx = blk * 16384 + i * 2048 + t * 8;
      u16 tmp[8];
#pragma unroll
      for (int j = 0; j < 8; ++j) tmp[j] = f2bf(x[idx + j]);
      *(uint4_a*)&xbf[idx] = *(const uint4_a*)tmp;
    }
  }
}

// ---------------- 64x128 bf16 GEMM, B^T input, async staging -----------------
// XOR chunk swizzle: chunk c of row m at slot m*8 + ((c+m)&7). ofp32: fp32
// epilogue (d_out). vtb: waves covering cols>=1088 also scatter V^T.
__global__ __launch_bounds__(256) void gemm_bt_bias(
    const u16* __restrict__ A, const u16* __restrict__ Bt,
    const float* __restrict__ bias, void* __restrict__ C, int K, int ldc,
    int ofp32, u16* __restrict__ vtb) {
  __shared__ __align__(16) u16 As[64 * 64];
  __shared__ __align__(16) u16 Bs[128 * 64];
  const int tn0 = blockIdx.x * 128, tm0 = blockIdx.y * 64;
  const int tid = threadIdx.x, wave = tid >> 6, lane = tid & 63;
  const int quad = lane >> 4, l16 = lane & 15;
  const int wm = wave & 1, wn = wave >> 1;

  f4 acc[2][4];
#pragma unroll
  for (int i = 0; i < 2; ++i)
#pragma unroll
    for (int j = 0; j < 4; ++j) acc[i][j] = f4{0.f, 0.f, 0.f, 0.f};

  int aslot[2], bslot[4]; size_t aoff[2], boff[4];
#pragma unroll
  for (int i = 0; i < 2; ++i) {
    int s = i * 256 + tid, m = s >> 3, kc = s & 7, c = (kc - m) & 7;
    aslot[i] = s; aoff[i] = (size_t)(tm0 + m) * K + c * 8;
  }
#pragma unroll
  for (int i = 0; i < 4; ++i) {
    int s = i * 256 + tid, n = s >> 3, kc = s & 7, c = (kc - n) & 7;
    bslot[i] = s; boff[i] = (size_t)(tn0 + n) * K + c * 8;
  }
  int ard[2][2], brd[4][2];
#pragma unroll
  for (int mi = 0; mi < 2; ++mi) {
    int m = wm * 32 + mi * 16 + l16;
#pragma unroll
    for (int kk = 0; kk < 2; ++kk)
      ard[mi][kk] = (m * 8 + (((kk * 4 + quad) + m) & 7)) * 8;
  }
#pragma unroll
  for (int ni = 0; ni < 4; ++ni) {
    int n = wn * 64 + ni * 16 + l16;
#pragma unroll
    for (int kk = 0; kk < 2; ++kk)
      brd[ni][kk] = (n * 8 + (((kk * 4 + quad) + n) & 7)) * 8;
  }

  const int kIt = K >> 6;
  for (int it = 0; it < kIt; ++it) {
    __syncthreads();
    const size_t kb = (size_t)it * 64;
#pragma unroll
    for (int i = 0; i < 2; ++i) async_cp16(&As[aslot[i] * 8], A + aoff[i] + kb);
#pragma unroll
    for (int i = 0; i < 4; ++i) async_cp16(&Bs[bslot[i] * 8], Bt + boff[i] + kb);
    __syncthreads();
#pragma unroll
    for (int kk = 0; kk < 2; ++kk) {
      bf8 af[2], bfr[4];
#pragma unroll
      for (int mi = 0; mi < 2; ++mi) af[mi] = *(const bf8_a*)&As[ard[mi][kk]];
#pragma unroll
      for (int ni = 0; ni < 4; ++ni) bfr[ni] = *(const bf8_a*)&Bs[brd[ni][kk]];
#pragma unroll
      for (int mi = 0; mi < 2; ++mi)
#pragma unroll
        for (int ni = 0; ni < 4; ++ni)
          acc[mi][ni] = __builtin_amdgcn_mfma_f32_16x16x32_bf16(
              af[mi], bfr[ni], acc[mi][ni], 0, 0, 0);
    }
  }

  float bv[4];
#pragma unroll
  for (int ni = 0; ni < 4; ++ni) bv[ni] = bias[tn0 + wn * 64 + ni * 16 + l16];
#pragma unroll
  for (int mi = 0; mi < 2; ++mi) {
    int row0 = tm0 + wm * 32 + mi * 16 + quad * 4;
#pragma unroll
    for (int ni = 0; ni < 4; ++ni) {
      int col = tn0 + wn * 64 + ni * 16 + l16;
      float vv[4];
#pragma unroll
      for (int r = 0; r < 4; ++r) vv[r] = acc[mi][ni][r] + bv[ni];
      if (ofp32) {
#pragma unroll
        for (int r = 0; r < 4; ++r)
          ((float*)C)[(size_t)(row0 + r) * ldc + col] = vv[r];
      } else {
#pragma unroll
        for (int r = 0; r < 4; ++r)
          ((u16*)C)[(size_t)(row0 + r) * ldc + col] = f2bf(vv[r]);
      }
      if (vtb != nullptr && col >= 1088) {
        int d = col - 1088, bb = row0 >> 11, s0 = row0 & 2047;
        uint2 pk;
        pk.x = pk2bf(vv[0], vv[1]);
        pk.y = pk2bf(vv[2], vv[3]);
        *(uint2_a*)&vtb[(size_t)(bb * 64 + d) * SLEN + s0] = pk;
      }
    }
  }
}

// ---------------- flash attention (MQA), split-K over key halves -------------
// Grid (16 qt, 32 bh, 2 ks) = 1024 blocks = 4/CU (LDS cap). No-max softmax
// partials are additive: each half writes unnormalized O (bf16) + l (fp32);
// reduce_o combines. 256 thr = 4 waves x 32 q-rows; fragment-major Kf/Vf.
__global__ __launch_bounds__(256, 4) void attn_kernel(
    const u16* __restrict__ qkv, const u16* __restrict__ vT,
    u16* __restrict__ Opart, float* __restrict__ lpart) {
  __shared__ __align__(16) u16 Kf[8192];    // K tile frag-major; Qf in prologue
  __shared__ __align__(16) u16 Vf[8192];
  __shared__ __align__(16) u16 Ps[4096];    // 4 waves x 1024 (one 32-key group)
  const int qt = blockIdx.x, bh = blockIdx.y, ks = blockIdx.z;
  const int b = bh >> 4, h = bh & 15;
  const int tid = threadIdx.x, wave = tid >> 6, lane = tid & 63;
  const int quad = lane >> 4, l16 = lane & 15;

  // Qf stage: chunk d = [kk:1][g:3][qd:2][r16:4]
#pragma unroll
  for (int i = 0; i < 4; ++i) {
    int d = i * 256 + tid;
    int kk = d >> 9, g = (d >> 6) & 7, qd = (d >> 4) & 3, r16 = d & 15;
    async_cp16(&Kf[d * 8],
               qkv + (size_t)(b * SLEN + qt * 128 + g * 16 + r16) * QLD +
                   h * HD + (kk * 4 + qd) * 8);
  }
  __syncthreads();
  bf8 bq[2][2];  // [nt][kk], B-frag rows wave*32 + nt*16 + l16
#pragma unroll
  for (int nt = 0; nt < 2; ++nt)
#pragma unroll
    for (int kk = 0; kk < 2; ++kk)
      bq[nt][kk] = *(const bf8_a*)&Kf[((kk * 8 + wave * 2 + nt) * 64 + lane) * 8];

  f4 acc_o[2][4];
#pragma unroll
  for (int i = 0; i < 2; ++i)
#pragma unroll
    for (int j = 0; j < 4; ++j) acc_o[i][j] = f4{0.f, 0.f, 0.f, 0.f};
  f4 lr4[2] = {f4{0.f, 0.f, 0.f, 0.f}, f4{0.f, 0.f, 0.f, 0.f}};
  const float C1 = 0.125f * 1.44269504089f;  // scale * log2(e)
  const int psb = wave * 1024;

  for (int kt = ks * 8; kt < ks * 8 + 8; ++kt) {
    __syncthreads();  // prior Kf/Vf reads (incl. bq prologue) complete
#pragma unroll
    for (int i = 0; i < 4; ++i) {
      int d = i * 256 + tid;
      int kk = d >> 9, k8 = (d >> 6) & 7, qd = (d >> 4) & 3, r16 = d & 15;
      async_cp16(&Kf[d * 8],
                 qkv + (size_t)(b * SLEN + kt * 128 + k8 * 16 + r16) * QLD +
                     EDIM + (kk * 4 + qd) * 8);
    }
#pragma unroll
    for (int i = 0; i < 4; ++i) {
      int d = i * 256 + tid;
      int k4 = d >> 8, ni = (d >> 6) & 3, qd = (d >> 4) & 3, r16 = d & 15;
      async_cp16(&Vf[d * 8],
                 vT + (size_t)(b * 64 + ni * 16 + r16) * SLEN + kt * 128 +
                     (k4 * 4 + qd) * 8);
    }
    __syncthreads();

    // per-32-key fused groups: QK -> softmax/pack -> wave-private Ps -> PV
#pragma unroll
    for (int k4 = 0; k4 < 4; ++k4) {
      f4 st[2][2];
#pragma unroll
      for (int j = 0; j < 2; ++j)
#pragma unroll
        for (int nt = 0; nt < 2; ++nt) st[j][nt] = f4{0.f, 0.f, 0.f, 0.f};
#pragma unroll
      for (int kk = 0; kk < 2; ++kk)
#pragma unroll
        for (int j = 0; j < 2; ++j) {
          bf8 ak = *(const bf8_a*)&Kf[((kk * 8 + k4 * 2 + j) * 64 + lane) * 8];
#pragma unroll
          for (int nt = 0; nt < 2; ++nt)
            st[j][nt] = __builtin_amdgcn_mfma_f32_16x16x32_bf16(
                ak, bq[nt][kk], st[j][nt], 0, 0, 0);
        }
#pragma unroll
      for (int nt = 0; nt < 2; ++nt)
#pragma unroll
        for (int j = 0; j < 2; ++j) {
          f4 pe;
          pe[0] = __builtin_amdgcn_exp2f(st[j][nt][0] * C1);
          pe[1] = __builtin_amdgcn_exp2f(st[j][nt][1] * C1);
          pe[2] = __builtin_amdgcn_exp2f(st[j][nt][2] * C1);
          pe[3] = __builtin_amdgcn_exp2f(st[j][nt][3] * C1);
          lr4[nt] += pe;
          uint2 pk;
          pk.x = pk2bf(pe[0], pe[1]);
          pk.y = pk2bf(pe[2], pe[3]);
          int qd2 = j * 2 + (quad >> 1);
          *(uint2_a*)&Ps[psb + ((nt * 4 + qd2) * 16 + l16) * 8 + (quad & 1) * 4] = pk;
        }
      asm volatile("" ::: "memory");  // Ps writes before PV reads (same wave)
      bf8 ap[2];
#pragma unroll
      for (int mt = 0; mt < 2; ++mt)
        ap[mt] = *(const bf8_a*)&Ps[psb + ((mt * 4 + quad) * 16 + l16) * 8];
#pragma unroll
      for (int ni = 0; ni < 4; ++ni) {
        bf8 bv = *(const bf8_a*)&Vf[((k4 * 4 + ni) * 64 + lane) * 8];
#pragma unroll
        for (int mt = 0; mt < 2; ++mt)
          acc_o[mt][ni] = __builtin_amdgcn_mfma_f32_16x16x32_bf16(
              ap[mt], bv, acc_o[mt][ni], 0, 0, 0);
      }
      asm volatile("" ::: "memory");  // PV reads before next group's Ps writes
    }
  }

  // store unnormalized partials: O bf16, l fp32
  const size_t pbase = (size_t)((ks * 32 + bh) * 16 + qt) * 128;
  float ls[2];
#pragma unroll
  for (int nt = 0; nt < 2; ++nt) {
    float s = (lr4[nt][0] + lr4[nt][1]) + (lr4[nt][2] + lr4[nt][3]);
    s += __shfl_xor(s, 16, 64);
    s += __shfl_xor(s, 32, 64);
    ls[nt] = s;
    if (quad == 0) lpart[pbase + wave * 32 + nt * 16 + l16] = s;
  }
#pragma unroll
  for (int mt = 0; mt < 2; ++mt)
#pragma unroll
    for (int r = 0; r < 4; ++r) {
      size_t row = pbase + wave * 32 + mt * 16 + quad * 4 + r;
#pragma unroll
      for (int ni = 0; ni < 4; ++ni)
        Opart[row * 64 + ni * 16 + l16] = f2bf(acc_o[mt][ni][r]);
    }
}

// ---------------- combine split-K halves: aob = (O0+O1)/(l0+l1) --------------
__global__ __launch_bounds__(256) void reduce_o(const u16* __restrict__ Op,
                                                const float* __restrict__ lp,
                                                u16* __restrict__ aob) {
  const int qt = blockIdx.x, bh = blockIdx.y, b = bh >> 4, h = bh & 15;
  const int t = threadIdx.x, r = t >> 1, dh = (t & 1) * 32;
  const size_t p0 = (size_t)(bh * 16 + qt) * 128;
  const size_t p1 = (size_t)((32 + bh) * 16 + qt) * 128;
  const float inv = 1.f / (lp[p0 + r] + lp[p1 + r]);
  const u16* o0 = Op + (p0 + r) * 64 + dh;
  const u16* o1 = Op + (p1 + r) * 64 + dh;
  u16* dst = aob + (size_t)(b * SLEN + qt * 128 + r) * EDIM + h * HD + dh;
#pragma unroll
  for (int c = 0; c < 4; ++c) {
    uint4 a = *(const uint4_a*)(o0 + c * 8);
    uint4 bb = *(const uint4_a*)(o1 + c * 8);
    const u16* pa = (const u16*)&a;
    const u16* pb = (const u16*)&bb;
    u16 outv[8];
#pragma unroll
    for (int j = 0; j < 8; ++j)
      outv[j] = f2bf((bf2f(pa[j]) + bf2f(pb[j])) * inv);
    *(uint4_a*)(dst + c * 8) = *(const uint4_a*)outv;
  }
}

// ---------------- host ------------------------------------------------------
extern "C" void kernel_launch(void* const* d_in, const int* in_sizes, int n_in,
                              void* d_out, int out_size, void* d_ws, size_t ws_size,
                              hipStream_t stream) {
  const float* x  = (const float*)d_in[0];
  const float* wq = (const float*)d_in[1];
  const float* bq = (const float*)d_in[2];
  const float* wk = (const float*)d_in[3];
  const float* bk = (const float*)d_in[4];
  const float* wv = (const float*)d_in[5];
  const float* bv = (const float*)d_in[6];
  const float* wo = (const float*)d_in[7];
  const float* bo = (const float*)d_in[8];

  char* ws = (char*)d_ws;
  size_t off = 0;
  auto carve = [&](size_t bytes) {
    void* p = ws + off;
    off = (off + bytes + 255) & ~(size_t)255;
    return p;
  };
  u16* xbf     = (u16*)carve((size_t)4096 * EDIM * 2);
  u16* wT      = (u16*)carve((size_t)1152 * 1024 * 2);  // packed [wq|wk|wv]^T
  u16* woT     = (u16*)carve((size_t)1024 * 1024 * 2);
  float* bQKV  = (float*)carve(1152 * 4);
  float* bOut  = (float*)carve(1024 * 4);
  u16* qkvb    = (u16*)carve((size_t)4096 * QLD * 2);
  u16* vTb     = (u16*)carve((size_t)2 * 64 * SLEN * 2);
  u16* aob     = (u16*)carve((size_t)4096 * EDIM * 2);
  u16* Opart   = (u16*)carve((size_t)2 * 32 * 16 * 128 * 64 * 2);  // 16.8 MB
  float* lpart = (float*)carve((size_t)2 * 32 * 16 * 128 * 4);     // 0.5 MB

  // prep: weight transposes + bias + x-convert (one grid)
  prep_w<<<dim3(16, 51), 256, 0, stream>>>(wq, wk, wv, wo, bq, bk, bv, bo, x,
                                           wT, woT, bQKV, bOut, xbf);

  // QKV projection (+ fused V-transpose): [4096][1024] @ [1024][1152]^T
  gemm_bt_bias<<<dim3(9, 64), 256, 0, stream>>>(xbf, wT, bQKV, qkvb, 1024, QLD,
                                                0, vTb);

  // flash attention, split-K over key halves
  attn_kernel<<<dim3(16, 32, 2), 256, 0, stream>>>(qkvb, vTb, Opart, lpart);
  reduce_o<<<dim3(16, 32), 256, 0, stream>>>(Opart, lpart, aob);

  // output projection + bo -> d_out (fp32)
  gemm_bt_bias<<<dim3(8, 64), 256, 0, stream>>>(aob, woT, bOut, d_out, 1024,
                                                1024, 1, nullptr);
}